// Round 12
// baseline (245.795 us; speedup 1.0000x reference)
//
#include <hip/hip_runtime.h>
#include <hip/hip_bf16.h>

// GCN restructured + fused, bf16 intermediates (R10/R6 structure; R12 = 4-edge
// ILP in the atomic pre-phase kernels):
//   h1 = relu((Ahat x) @ W1 + b1)   -- fused gather(fp32)+GEMM, K=32 -> F=64 bf16
//   h2 = relu((Ahat h1) @ W2 + b2)  -- fused gather(bf16)+GEMM, K=64 -> F=128 bf16
//   Spart = per-graph partial segment sums of (Ahat h2)  -- fused gather(bf16)+pool
//   out = ((sum(Spart)@W3)/cnt + b3) @ Wlin + blin

#define NN 100000
#define NE 800000
#define NG 512
#define PARTS 4

typedef unsigned int u32;

// RNE pack of two fp32 -> packed bf16x2 (lo in low half)
__device__ __forceinline__ u32 pack_bf2(float lo, float hi) {
    u32 ul = __float_as_uint(lo);
    u32 uh = __float_as_uint(hi);
    ul = (ul + 0x7fffu + ((ul >> 16) & 1u)) >> 16;
    uh = (uh + 0x7fffu + ((uh >> 16) & 1u)) & 0xffff0000u;
    return uh | ul;
}

// acc[0..7] += unpack8(v) * w
#define BF_FMA8(ACC, V, W_) do { \
    (ACC)[0] += __uint_as_float((V).x << 16) * (W_); \
    (ACC)[1] += __uint_as_float((V).x & 0xffff0000u) * (W_); \
    (ACC)[2] += __uint_as_float((V).y << 16) * (W_); \
    (ACC)[3] += __uint_as_float((V).y & 0xffff0000u) * (W_); \
    (ACC)[4] += __uint_as_float((V).z << 16) * (W_); \
    (ACC)[5] += __uint_as_float((V).z & 0xffff0000u) * (W_); \
    (ACC)[6] += __uint_as_float((V).w << 16) * (W_); \
    (ACC)[7] += __uint_as_float((V).w & 0xffff0000u) * (W_); \
} while (0)

#define FMA4(A, H, W_) do { (A).x += (H).x * (W_); (A).y += (H).y * (W_); \
                            (A).z += (H).z * (W_); (A).w += (H).w * (W_); } while (0)

// ---------------- degree: 4 edges/thread, int4 loads ----------------
__global__ __launch_bounds__(256) void deg_count(const int* __restrict__ dst,
                                                 int* __restrict__ deg, int nE4) {
    int i = blockIdx.x * 256 + threadIdx.x;
    if (i >= nE4) return;
    const int4 d4 = *reinterpret_cast<const int4*>(&dst[i * 4]);
    atomicAdd(&deg[d4.x], 1);
    atomicAdd(&deg[d4.y], 1);
    atomicAdd(&deg[d4.z], 1);
    atomicAdd(&deg[d4.w], 1);
}

// ---------------- exclusive scan of deg -> row_ptr ----------------
__global__ __launch_bounds__(256) void scanA(const int* __restrict__ deg,
                                             int* __restrict__ ex,
                                             int* __restrict__ bsum, int n) {
    __shared__ int sdata[256];
    const int t = threadIdx.x;
    const int base = blockIdx.x * 1024;
    const int idx = base + t * 4;
    int v[4];
#pragma unroll
    for (int k = 0; k < 4; ++k) v[k] = (idx + k < n) ? deg[idx + k] : 0;
    int ts = v[0] + v[1] + v[2] + v[3];
    sdata[t] = ts;
    __syncthreads();
    for (int off = 1; off < 256; off <<= 1) {
        int val = (t >= off) ? sdata[t - off] : 0;
        __syncthreads();
        sdata[t] += val;
        __syncthreads();
    }
    int run = sdata[t] - ts;
    if (t == 255) bsum[blockIdx.x] = sdata[255];
#pragma unroll
    for (int k = 0; k < 4; ++k) {
        if (idx + k < n) ex[idx + k] = run;
        run += v[k];
    }
}

__global__ __launch_bounds__(128) void scanB(int* __restrict__ bsum, int nb) {
    __shared__ int s[128];
    const int t = threadIdx.x;
    int orig = (t < nb) ? bsum[t] : 0;
    s[t] = orig;
    __syncthreads();
    for (int off = 1; off < 128; off <<= 1) {
        int val = (t >= off) ? s[t - off] : 0;
        __syncthreads();
        s[t] += val;
        __syncthreads();
    }
    if (t < nb) bsum[t] = s[t] - orig;
}

__global__ __launch_bounds__(256) void scanC(int* __restrict__ rp,
                                             const int* __restrict__ bsum,
                                             int* __restrict__ cursor,
                                             const int* __restrict__ deg,
                                             float* __restrict__ dinv,
                                             int n, int total) {
    int i = blockIdx.x * 256 + threadIdx.x;
    if (i < n) {
        int v = rp[i] + bsum[i >> 10];
        rp[i] = v;
        cursor[i] = v;
        dinv[i] = rsqrtf((float)deg[i] + 1.0f);
    }
    if (i == n) rp[n] = total;
}

// ---------------- CSR fill: 4 edges/thread, int4 loads ----------------
__global__ __launch_bounds__(256) void fill_csr(const int* __restrict__ ei,
                                                const float* __restrict__ dinv,
                                                int* __restrict__ cursor,
                                                int2* __restrict__ cw, int nE4) {
    int i = blockIdx.x * 256 + threadIdx.x;
    if (i >= nE4) return;
    const int4 s4 = *reinterpret_cast<const int4*>(&ei[i * 4]);
    const int4 d4 = *reinterpret_cast<const int4*>(&ei[NE + i * 4]);
    const int p0 = atomicAdd(&cursor[d4.x], 1);
    const int p1 = atomicAdd(&cursor[d4.y], 1);
    const int p2 = atomicAdd(&cursor[d4.z], 1);
    const int p3 = atomicAdd(&cursor[d4.w], 1);
    cw[p0] = make_int2(s4.x, __float_as_int(dinv[s4.x] * dinv[d4.x]));
    cw[p1] = make_int2(s4.y, __float_as_int(dinv[s4.y] * dinv[d4.y]));
    cw[p2] = make_int2(s4.z, __float_as_int(dinv[s4.z] * dinv[d4.z]));
    cw[p3] = make_int2(s4.w, __float_as_int(dinv[s4.w] * dinv[d4.w]));
}

// ---------------- layer 1: h1 = relu((Ahat x)@W1 + b1), fp32 in, bf16 out ----
__global__ __launch_bounds__(256) void gather_gemm_l1(const float* __restrict__ X,
                                                      const int* __restrict__ rp,
                                                      const int2* __restrict__ cw,
                                                      const float* __restrict__ dinv,
                                                      const float* __restrict__ W,
                                                      const float* __restrict__ bias,
                                                      u32* __restrict__ out, int n) {
    constexpr int AS = 36;
    __shared__ float agg[32 * AS];
    __shared__ float Wl[32 * 64];
    float4 wr[2];
#pragma unroll
    for (int i = 0; i < 2; ++i)
        wr[i] = *reinterpret_cast<const float4*>(&W[(threadIdx.x + i * 256) * 4]);

    const int nl = threadIdx.x >> 3;
    const int j = (threadIdx.x & 7) * 4;
    const int node = blockIdx.x * 32 + nl;
    float4 a0 = make_float4(0.f, 0.f, 0.f, 0.f);
    float4 a1 = a0, a2 = a0, a3 = a0;
    if (node < n) {
        const float di = dinv[node];
        const float c = di * di;
        const float4 sv = *reinterpret_cast<const float4*>(&X[(long long)node * 32 + j]);
        FMA4(a0, sv, c);
        int e = rp[node];
        const int end = rp[node + 1];
        for (; e + 4 <= end; e += 4) {
            const int2 c0 = cw[e], c1 = cw[e + 1], c2 = cw[e + 2], c3 = cw[e + 3];
            const float4 h0 = *reinterpret_cast<const float4*>(&X[(long long)c0.x * 32 + j]);
            const float4 h1 = *reinterpret_cast<const float4*>(&X[(long long)c1.x * 32 + j]);
            const float4 h2 = *reinterpret_cast<const float4*>(&X[(long long)c2.x * 32 + j]);
            const float4 h3 = *reinterpret_cast<const float4*>(&X[(long long)c3.x * 32 + j]);
            FMA4(a0, h0, __int_as_float(c0.y));
            FMA4(a1, h1, __int_as_float(c1.y));
            FMA4(a2, h2, __int_as_float(c2.y));
            FMA4(a3, h3, __int_as_float(c3.y));
        }
        if (e + 2 <= end) {
            const int2 c0 = cw[e], c1 = cw[e + 1];
            const float4 h0 = *reinterpret_cast<const float4*>(&X[(long long)c0.x * 32 + j]);
            const float4 h1 = *reinterpret_cast<const float4*>(&X[(long long)c1.x * 32 + j]);
            FMA4(a0, h0, __int_as_float(c0.y));
            FMA4(a1, h1, __int_as_float(c1.y));
            e += 2;
        }
        if (e < end) {
            const int2 c0 = cw[e];
            const float4 h0 = *reinterpret_cast<const float4*>(&X[(long long)c0.x * 32 + j]);
            FMA4(a0, h0, __int_as_float(c0.y));
        }
        a0.x += a1.x + a2.x + a3.x; a0.y += a1.y + a2.y + a3.y;
        a0.z += a1.z + a2.z + a3.z; a0.w += a1.w + a2.w + a3.w;
    }
    *reinterpret_cast<float4*>(&agg[nl * AS + j]) = a0;
#pragma unroll
    for (int i = 0; i < 2; ++i)
        *reinterpret_cast<float4*>(&Wl[(threadIdx.x + i * 256) * 4]) = wr[i];
    __syncthreads();

    // phase B: K=32, F=64
    const int r0 = (threadIdx.x >> 4) * 2;
    const int cg = (threadIdx.x & 15) * 4;
    float4 o0 = make_float4(0.f, 0.f, 0.f, 0.f);
    float4 o1 = o0;
#pragma unroll 8
    for (int k = 0; k < 32; ++k) {
        const float4 wv = *reinterpret_cast<const float4*>(&Wl[k * 64 + cg]);
        const float x0 = agg[r0 * AS + k];
        const float x1 = agg[(r0 + 1) * AS + k];
        FMA4(o0, wv, x0);
        FMA4(o1, wv, x1);
    }
    const float4 bv = *reinterpret_cast<const float4*>(&bias[cg]);
    o0.x = fmaxf(o0.x + bv.x, 0.f); o0.y = fmaxf(o0.y + bv.y, 0.f);
    o0.z = fmaxf(o0.z + bv.z, 0.f); o0.w = fmaxf(o0.w + bv.w, 0.f);
    o1.x = fmaxf(o1.x + bv.x, 0.f); o1.y = fmaxf(o1.y + bv.y, 0.f);
    o1.z = fmaxf(o1.z + bv.z, 0.f); o1.w = fmaxf(o1.w + bv.w, 0.f);
    const int row0 = blockIdx.x * 32 + r0;
    if (row0 < n)
        *reinterpret_cast<uint2*>(&out[(long long)row0 * 32 + (cg >> 1)]) =
            make_uint2(pack_bf2(o0.x, o0.y), pack_bf2(o0.z, o0.w));
    if (row0 + 1 < n)
        *reinterpret_cast<uint2*>(&out[(long long)(row0 + 1) * 32 + (cg >> 1)]) =
            make_uint2(pack_bf2(o1.x, o1.y), pack_bf2(o1.z, o1.w));
}

// ---------------- layer 2: h2 = relu((Ahat h1)@W2 + b2), bf16 in/out ----------
__global__ __launch_bounds__(256) void gather_gemm_l2(const u32* __restrict__ X,
                                                      const int* __restrict__ rp,
                                                      const int2* __restrict__ cw,
                                                      const float* __restrict__ dinv,
                                                      const float* __restrict__ W,
                                                      const float* __restrict__ bias,
                                                      u32* __restrict__ out, int n) {
    constexpr int AS = 68;
    __shared__ float agg[32 * AS];
    __shared__ float Wl[64 * 128];
    float4 wr[8];
#pragma unroll
    for (int i = 0; i < 8; ++i)
        wr[i] = *reinterpret_cast<const float4*>(&W[(threadIdx.x + i * 256) * 4]);

    const int nl = threadIdx.x >> 3;
    const int j = threadIdx.x & 7;         // feature octet
    const int node = blockIdx.x * 32 + nl;
    float a0[8], a1[8], a2[8], a3[8];
#pragma unroll
    for (int q = 0; q < 8; ++q) { a0[q] = 0.f; a1[q] = 0.f; a2[q] = 0.f; a3[q] = 0.f; }
    if (node < n) {
        const float di = dinv[node];
        const float c = di * di;
        const uint4 sv = *reinterpret_cast<const uint4*>(&X[(long long)node * 32 + j * 4]);
        BF_FMA8(a0, sv, c);
        int e = rp[node];
        const int end = rp[node + 1];
        for (; e + 4 <= end; e += 4) {
            const int2 c0 = cw[e], c1 = cw[e + 1], c2 = cw[e + 2], c3 = cw[e + 3];
            const uint4 h0 = *reinterpret_cast<const uint4*>(&X[(long long)c0.x * 32 + j * 4]);
            const uint4 h1 = *reinterpret_cast<const uint4*>(&X[(long long)c1.x * 32 + j * 4]);
            const uint4 h2 = *reinterpret_cast<const uint4*>(&X[(long long)c2.x * 32 + j * 4]);
            const uint4 h3 = *reinterpret_cast<const uint4*>(&X[(long long)c3.x * 32 + j * 4]);
            BF_FMA8(a0, h0, __int_as_float(c0.y));
            BF_FMA8(a1, h1, __int_as_float(c1.y));
            BF_FMA8(a2, h2, __int_as_float(c2.y));
            BF_FMA8(a3, h3, __int_as_float(c3.y));
        }
        if (e + 2 <= end) {
            const int2 c0 = cw[e], c1 = cw[e + 1];
            const uint4 h0 = *reinterpret_cast<const uint4*>(&X[(long long)c0.x * 32 + j * 4]);
            const uint4 h1 = *reinterpret_cast<const uint4*>(&X[(long long)c1.x * 32 + j * 4]);
            BF_FMA8(a0, h0, __int_as_float(c0.y));
            BF_FMA8(a1, h1, __int_as_float(c1.y));
            e += 2;
        }
        if (e < end) {
            const int2 c0 = cw[e];
            const uint4 h0 = *reinterpret_cast<const uint4*>(&X[(long long)c0.x * 32 + j * 4]);
            BF_FMA8(a0, h0, __int_as_float(c0.y));
        }
#pragma unroll
        for (int q = 0; q < 8; ++q) a0[q] += a1[q] + a2[q] + a3[q];
    }
    *reinterpret_cast<float4*>(&agg[nl * AS + j * 8]) =
        make_float4(a0[0], a0[1], a0[2], a0[3]);
    *reinterpret_cast<float4*>(&agg[nl * AS + j * 8 + 4]) =
        make_float4(a0[4], a0[5], a0[6], a0[7]);
#pragma unroll
    for (int i = 0; i < 8; ++i)
        *reinterpret_cast<float4*>(&Wl[(threadIdx.x + i * 256) * 4]) = wr[i];
    __syncthreads();

    // phase B: K=64, F=128, 4 rows x 4 cols
    const int r0 = (threadIdx.x >> 5) * 4;
    const int cg = (threadIdx.x & 31) * 4;
    float4 o0 = make_float4(0.f, 0.f, 0.f, 0.f);
    float4 o1 = o0, o2 = o0, o3 = o0;
#pragma unroll 8
    for (int k = 0; k < 64; ++k) {
        const float4 wv = *reinterpret_cast<const float4*>(&Wl[k * 128 + cg]);
        const float x0 = agg[(r0 + 0) * AS + k];
        const float x1 = agg[(r0 + 1) * AS + k];
        const float x2 = agg[(r0 + 2) * AS + k];
        const float x3 = agg[(r0 + 3) * AS + k];
        FMA4(o0, wv, x0);
        FMA4(o1, wv, x1);
        FMA4(o2, wv, x2);
        FMA4(o3, wv, x3);
    }
    const float4 bv = *reinterpret_cast<const float4*>(&bias[cg]);
    const int row0 = blockIdx.x * 32 + r0;
    float4 oo[4] = {o0, o1, o2, o3};
#pragma unroll
    for (int r = 0; r < 4; ++r) {
        float4 o = oo[r];
        o.x = fmaxf(o.x + bv.x, 0.f); o.y = fmaxf(o.y + bv.y, 0.f);
        o.z = fmaxf(o.z + bv.z, 0.f); o.w = fmaxf(o.w + bv.w, 0.f);
        if (row0 + r < n)
            *reinterpret_cast<uint2*>(&out[(long long)(row0 + r) * 64 + (cg >> 1)]) =
                make_uint2(pack_bf2(o.x, o.y), pack_bf2(o.z, o.w));
    }
}

// ---------------- fused layer-3 gather(bf16) + pool partials ----------------
__device__ __forceinline__ int lower_bound_i(const int* __restrict__ a, int n, int key) {
    int lo = 0, hi = n;
    while (lo < hi) {
        int mid = (lo + hi) >> 1;
        if (a[mid] < key) lo = mid + 1; else hi = mid;
    }
    return lo;
}

__global__ __launch_bounds__(256) void gather_pool(const u32* __restrict__ H,
                                                   const int* __restrict__ rp,
                                                   const int2* __restrict__ cw,
                                                   const float* __restrict__ dinv,
                                                   const int* __restrict__ batch,
                                                   float* __restrict__ Spart, int n) {
    __shared__ float red[16 * 128];
    const int g = blockIdx.x / PARTS;
    const int part = blockIdx.x % PARTS;
    const int slot = threadIdx.x >> 4;     // 16 slots
    const int j = threadIdx.x & 15;        // feature octet 0..15
    const int start = lower_bound_i(batch, n, g);
    const int end = lower_bound_i(batch, n, g + 1);
    float a0[8], a1[8], a2[8], a3[8];
#pragma unroll
    for (int q = 0; q < 8; ++q) { a0[q] = 0.f; a1[q] = 0.f; a2[q] = 0.f; a3[q] = 0.f; }
    for (int node = start + part * 16 + slot; node < end; node += PARTS * 16) {
        const float di = dinv[node];
        const float c = di * di;
        const uint4 sv = *reinterpret_cast<const uint4*>(&H[(long long)node * 64 + j * 4]);
        BF_FMA8(a0, sv, c);
        int e = rp[node];
        const int eend = rp[node + 1];
        for (; e + 4 <= eend; e += 4) {
            const int2 c0 = cw[e], c1 = cw[e + 1], c2 = cw[e + 2], c3 = cw[e + 3];
            const uint4 h0 = *reinterpret_cast<const uint4*>(&H[(long long)c0.x * 64 + j * 4]);
            const uint4 h1 = *reinterpret_cast<const uint4*>(&H[(long long)c1.x * 64 + j * 4]);
            const uint4 h2 = *reinterpret_cast<const uint4*>(&H[(long long)c2.x * 64 + j * 4]);
            const uint4 h3 = *reinterpret_cast<const uint4*>(&H[(long long)c3.x * 64 + j * 4]);
            BF_FMA8(a0, h0, __int_as_float(c0.y));
            BF_FMA8(a1, h1, __int_as_float(c1.y));
            BF_FMA8(a2, h2, __int_as_float(c2.y));
            BF_FMA8(a3, h3, __int_as_float(c3.y));
        }
        if (e + 2 <= eend) {
            const int2 c0 = cw[e], c1 = cw[e + 1];
            const uint4 h0 = *reinterpret_cast<const uint4*>(&H[(long long)c0.x * 64 + j * 4]);
            const uint4 h1 = *reinterpret_cast<const uint4*>(&H[(long long)c1.x * 64 + j * 4]);
            BF_FMA8(a0, h0, __int_as_float(c0.y));
            BF_FMA8(a1, h1, __int_as_float(c1.y));
            e += 2;
        }
        if (e < eend) {
            const int2 c0 = cw[e];
            const uint4 h0 = *reinterpret_cast<const uint4*>(&H[(long long)c0.x * 64 + j * 4]);
            BF_FMA8(a0, h0, __int_as_float(c0.y));
        }
    }
#pragma unroll
    for (int q = 0; q < 8; ++q) a0[q] += a1[q] + a2[q] + a3[q];
    *reinterpret_cast<float4*>(&red[slot * 128 + j * 8]) =
        make_float4(a0[0], a0[1], a0[2], a0[3]);
    *reinterpret_cast<float4*>(&red[slot * 128 + j * 8 + 4]) =
        make_float4(a0[4], a0[5], a0[6], a0[7]);
    __syncthreads();
    const int t = threadIdx.x;
    if (t < 128) {
        float s = 0.f;
#pragma unroll
        for (int sl = 0; sl < 16; ++sl) s += red[sl * 128 + t];
        Spart[(long long)blockIdx.x * 128 + t] = s;
    }
}

// ---------------- final ----------------
__global__ __launch_bounds__(256) void final_k(const float* __restrict__ Spart,
                                               const int* __restrict__ batch,
                                               const float* __restrict__ W3,
                                               const float* __restrict__ b3,
                                               const float* __restrict__ Wlin,
                                               const float* __restrict__ blin,
                                               float* __restrict__ out, int n) {
    __shared__ float srow[128];
    __shared__ float prow[256];
    const int g = blockIdx.x;
    const int t = threadIdx.x;
    if (t < 128) {
        float s = 0.f;
#pragma unroll
        for (int p = 0; p < PARTS; ++p)
            s += Spart[(long long)(g * PARTS + p) * 128 + t];
        srow[t] = s;
    }
    __syncthreads();
    const int start = lower_bound_i(batch, n, g);
    const int end = lower_bound_i(batch, n, g + 1);
    const float cnt = (float)(end - start);
    const float inv = 1.0f / fmaxf(cnt, 1.0f);
    const float bscale = cnt * inv;
    float p = 0.f;
    for (int k = 0; k < 128; ++k) p += srow[k] * W3[k * 256 + t];
    prow[t] = p * inv + b3[t] * bscale;
    __syncthreads();
    if (t < 10) {
        float a = blin[t];
        for (int f = 0; f < 256; ++f) a += prow[f] * Wlin[f * 10 + t];
        out[g * 10 + t] = a;
    }
}

extern "C" void kernel_launch(void* const* d_in, const int* in_sizes, int n_in,
                              void* d_out, int out_size, void* d_ws, size_t ws_size,
                              hipStream_t stream) {
    const float* x     = (const float*)d_in[0];
    const int*   ei    = (const int*)d_in[1];
    const int*   batch = (const int*)d_in[2];
    const float* W1    = (const float*)d_in[3];
    const float* bc1   = (const float*)d_in[4];
    const float* W2    = (const float*)d_in[5];
    const float* bc2   = (const float*)d_in[6];
    const float* W3    = (const float*)d_in[7];
    const float* bc3   = (const float*)d_in[8];
    const float* Wlin  = (const float*)d_in[9];
    const float* blin  = (const float*)d_in[10];
    float* out = (float*)d_out;

    char* w = (char*)d_ws;
    int*   deg    = (int*)w;               w += 131072 * 4;
    int*   rp     = (int*)w;               w += 131072 * 4;
    int*   cursor = (int*)w;               w += 131072 * 4;
    int*   bsum   = (int*)w;               w += 256 * 4;
    float* dinv   = (float*)w;             w += 131072 * 4;
    int2*  cw     = (int2*)w;              w += (long long)NE * 8;
    u32*   Q      = (u32*)w;               w += (long long)NN * 64 * 2;   // h1 bf16
    u32*   P      = (u32*)w;               w += (long long)NN * 128 * 2;  // h2 bf16
    float* Spart  = (float*)w;             w += (long long)NG * PARTS * 128 * 4;

    const int nbScanA = (NN + 1023) / 1024;
    const int nE4 = NE / 4;   // 200000, exact

    hipMemsetAsync(deg, 0, NN * sizeof(int), stream);
    deg_count<<<(nE4 + 255) / 256, 256, 0, stream>>>(ei + NE, deg, nE4);
    scanA<<<nbScanA, 256, 0, stream>>>(deg, rp, bsum, NN);
    scanB<<<1, 128, 0, stream>>>(bsum, nbScanA);
    scanC<<<(NN + 256) / 256, 256, 0, stream>>>(rp, bsum, cursor, deg, dinv, NN, NE);
    fill_csr<<<(nE4 + 255) / 256, 256, 0, stream>>>(ei, dinv, cursor, cw, nE4);

    gather_gemm_l1<<<(NN + 31) / 32, 256, 0, stream>>>(x, rp, cw, dinv, W1, bc1, Q, NN);
    gather_gemm_l2<<<(NN + 31) / 32, 256, 0, stream>>>(Q, rp, cw, dinv, W2, bc2, P, NN);
    gather_pool<<<NG * PARTS, 256, 0, stream>>>(P, rp, cw, dinv, batch, Spart, NN);
    final_k<<<NG, 256, 0, stream>>>(Spart, batch, W3, bc3, Wlin, blin, out, NN);
}

// Round 13
// 192.915 us; speedup vs baseline: 1.2741x; 1.2741x over previous
//
#include <hip/hip_runtime.h>
#include <hip/hip_bf16.h>

// GCN, bucket-CSR + pre-scaled rows (R13):
//   g_x = bf16(dinv * x)                         -- prep (also computes dinv)
//   agg_d = dinv_d*(g_d + sum g_s)  == Ahat h    -- weightless gather (pure adds)
//   g1 = bf16(dinv * relu(agg@W1+b1))            -- scale folded into epilogue
//   g2 = bf16(dinv * relu(agg1@W2+b2))
//   Spart = per-graph partial sums of dinv_d*(g2_d + sum g2_s)
//   out = ((S@W3)/cnt + b3) @ Wlin + blin
// CSR: fixed 64-slot buckets, src only (4B/edge); one atomic pass (no scan).

#define NN 100000
#define NE 800000
#define NG 512
#define PARTS 4
#define CAP 64        // bucket capacity (max in-degree; Poisson(8) tail << 64)

typedef unsigned int u32;

// RNE pack of two fp32 -> packed bf16x2 (lo in low half)
__device__ __forceinline__ u32 pack_bf2(float lo, float hi) {
    u32 ul = __float_as_uint(lo);
    u32 uh = __float_as_uint(hi);
    ul = (ul + 0x7fffu + ((ul >> 16) & 1u)) >> 16;
    uh = (uh + 0x7fffu + ((uh >> 16) & 1u)) & 0xffff0000u;
    return uh | ul;
}

// acc[0..7] += unpack8(v)   (v: uint4 of 8 bf16) -- weightless add
#define BF_ADD8(ACC, V) do { \
    (ACC)[0] += __uint_as_float((V).x << 16); \
    (ACC)[1] += __uint_as_float((V).x & 0xffff0000u); \
    (ACC)[2] += __uint_as_float((V).y << 16); \
    (ACC)[3] += __uint_as_float((V).y & 0xffff0000u); \
    (ACC)[4] += __uint_as_float((V).z << 16); \
    (ACC)[5] += __uint_as_float((V).z & 0xffff0000u); \
    (ACC)[6] += __uint_as_float((V).w << 16); \
    (ACC)[7] += __uint_as_float((V).w & 0xffff0000u); \
} while (0)

// acc[0..3] += unpack4(v)   (v: uint2 of 4 bf16)
#define BF_ADD4(ACC, V) do { \
    (ACC)[0] += __uint_as_float((V).x << 16); \
    (ACC)[1] += __uint_as_float((V).x & 0xffff0000u); \
    (ACC)[2] += __uint_as_float((V).y << 16); \
    (ACC)[3] += __uint_as_float((V).y & 0xffff0000u); \
} while (0)

#define FMA4(A, H, W_) do { (A).x += (H).x * (W_); (A).y += (H).y * (W_); \
                            (A).z += (H).z * (W_); (A).w += (H).w * (W_); } while (0)

// ---------------- bucket fill: cnt[d]++ places src; counts degree too --------
__global__ __launch_bounds__(256) void fill_bucket(const int* __restrict__ ei,
                                                   int* __restrict__ cnt,
                                                   int* __restrict__ cs, int nE) {
    int e = blockIdx.x * 256 + threadIdx.x;
    if (e >= nE) return;
    const int s = ei[e];
    const int d = ei[nE + e];
    const int c = atomicAdd(&cnt[d], 1);
    if (c < CAP) cs[(d << 6) + c] = s;
}

// ---------------- prep: dinv = rsqrt(cnt+1); xg = bf16(x * dinv) -------------
__global__ __launch_bounds__(256) void prep(const float* __restrict__ x,
                                            const int* __restrict__ cnt,
                                            float* __restrict__ dinv,
                                            u32* __restrict__ xg, int n8) {
    int i = blockIdx.x * 256 + threadIdx.x;   // over n*8 quartets
    if (i >= n8) return;
    const int node = i >> 3;
    const int j = i & 7;
    const float di = rsqrtf((float)cnt[node] + 1.0f);
    if (j == 0) dinv[node] = di;
    const float4 v = *reinterpret_cast<const float4*>(&x[(long long)node * 32 + j * 4]);
    *reinterpret_cast<uint2*>(&xg[(long long)node * 16 + j * 2]) =
        make_uint2(pack_bf2(v.x * di, v.y * di), pack_bf2(v.z * di, v.w * di));
}

// ---------------- layer 1: g1 = dinv*relu((Ahat x)@W1 + b1), bf16 in/out -----
__global__ __launch_bounds__(256) void gather_gemm_l1(const u32* __restrict__ X,
                                                      const int* __restrict__ cnt,
                                                      const int* __restrict__ cs,
                                                      const float* __restrict__ dinv,
                                                      const float* __restrict__ W,
                                                      const float* __restrict__ bias,
                                                      u32* __restrict__ out, int n) {
    constexpr int AS = 36;
    __shared__ float agg[32 * AS];
    __shared__ float Wl[32 * 64];
    float4 wr[2];
#pragma unroll
    for (int i = 0; i < 2; ++i)
        wr[i] = *reinterpret_cast<const float4*>(&W[(threadIdx.x + i * 256) * 4]);

    const int nl = threadIdx.x >> 3;
    const int j = threadIdx.x & 7;     // 4-feat group (uint2 = 4 bf16)
    const int node = blockIdx.x * 32 + nl;
    float a0[4], a1[4], a2[4], a3[4];
#pragma unroll
    for (int q = 0; q < 4; ++q) { a0[q] = 0.f; a1[q] = 0.f; a2[q] = 0.f; a3[q] = 0.f; }
    if (node < n) {
        const float di = dinv[node];
        const uint2 sv = *reinterpret_cast<const uint2*>(&X[(long long)node * 16 + j * 2]);
        BF_ADD4(a0, sv);
        const int* bp = cs + (node << 6);
        int end = cnt[node]; end = (end < CAP) ? end : CAP;
        int e = 0;
        for (; e + 4 <= end; e += 4) {
            const int s0 = bp[e], s1 = bp[e + 1], s2 = bp[e + 2], s3 = bp[e + 3];
            const uint2 h0 = *reinterpret_cast<const uint2*>(&X[(long long)s0 * 16 + j * 2]);
            const uint2 h1 = *reinterpret_cast<const uint2*>(&X[(long long)s1 * 16 + j * 2]);
            const uint2 h2 = *reinterpret_cast<const uint2*>(&X[(long long)s2 * 16 + j * 2]);
            const uint2 h3 = *reinterpret_cast<const uint2*>(&X[(long long)s3 * 16 + j * 2]);
            BF_ADD4(a0, h0);
            BF_ADD4(a1, h1);
            BF_ADD4(a2, h2);
            BF_ADD4(a3, h3);
        }
        if (e + 2 <= end) {
            const int s0 = bp[e], s1 = bp[e + 1];
            const uint2 h0 = *reinterpret_cast<const uint2*>(&X[(long long)s0 * 16 + j * 2]);
            const uint2 h1 = *reinterpret_cast<const uint2*>(&X[(long long)s1 * 16 + j * 2]);
            BF_ADD4(a0, h0);
            BF_ADD4(a1, h1);
            e += 2;
        }
        if (e < end) {
            const int s0 = bp[e];
            const uint2 h0 = *reinterpret_cast<const uint2*>(&X[(long long)s0 * 16 + j * 2]);
            BF_ADD4(a0, h0);
        }
#pragma unroll
        for (int q = 0; q < 4; ++q) a0[q] = di * (a0[q] + a1[q] + a2[q] + a3[q]);
    }
    *reinterpret_cast<float4*>(&agg[nl * AS + j * 4]) =
        make_float4(a0[0], a0[1], a0[2], a0[3]);
#pragma unroll
    for (int i = 0; i < 2; ++i)
        *reinterpret_cast<float4*>(&Wl[(threadIdx.x + i * 256) * 4]) = wr[i];
    __syncthreads();

    // phase B: K=32, F=64, 2 rows x 4 cols
    const int r0 = (threadIdx.x >> 4) * 2;
    const int cg = (threadIdx.x & 15) * 4;
    float4 o0 = make_float4(0.f, 0.f, 0.f, 0.f);
    float4 o1 = o0;
#pragma unroll 8
    for (int k = 0; k < 32; ++k) {
        const float4 wv = *reinterpret_cast<const float4*>(&Wl[k * 64 + cg]);
        const float x0 = agg[r0 * AS + k];
        const float x1 = agg[(r0 + 1) * AS + k];
        FMA4(o0, wv, x0);
        FMA4(o1, wv, x1);
    }
    const float4 bv = *reinterpret_cast<const float4*>(&bias[cg]);
    const int row0 = blockIdx.x * 32 + r0;
    if (row0 < n) {
        const float dr = dinv[row0];
        float ox = fmaxf(o0.x + bv.x, 0.f) * dr, oy = fmaxf(o0.y + bv.y, 0.f) * dr;
        float oz = fmaxf(o0.z + bv.z, 0.f) * dr, ow = fmaxf(o0.w + bv.w, 0.f) * dr;
        *reinterpret_cast<uint2*>(&out[(long long)row0 * 32 + (cg >> 1)]) =
            make_uint2(pack_bf2(ox, oy), pack_bf2(oz, ow));
    }
    if (row0 + 1 < n) {
        const float dr = dinv[row0 + 1];
        float ox = fmaxf(o1.x + bv.x, 0.f) * dr, oy = fmaxf(o1.y + bv.y, 0.f) * dr;
        float oz = fmaxf(o1.z + bv.z, 0.f) * dr, ow = fmaxf(o1.w + bv.w, 0.f) * dr;
        *reinterpret_cast<uint2*>(&out[(long long)(row0 + 1) * 32 + (cg >> 1)]) =
            make_uint2(pack_bf2(ox, oy), pack_bf2(oz, ow));
    }
}

// ---------------- layer 2: g2 = dinv*relu((Ahat h1)@W2 + b2), bf16 in/out ----
__global__ __launch_bounds__(256) void gather_gemm_l2(const u32* __restrict__ X,
                                                      const int* __restrict__ cnt,
                                                      const int* __restrict__ cs,
                                                      const float* __restrict__ dinv,
                                                      const float* __restrict__ W,
                                                      const float* __restrict__ bias,
                                                      u32* __restrict__ out, int n) {
    constexpr int AS = 68;
    __shared__ float agg[32 * AS];
    __shared__ float Wl[64 * 128];
    float4 wr[8];
#pragma unroll
    for (int i = 0; i < 8; ++i)
        wr[i] = *reinterpret_cast<const float4*>(&W[(threadIdx.x + i * 256) * 4]);

    const int nl = threadIdx.x >> 3;
    const int j = threadIdx.x & 7;         // feature octet
    const int node = blockIdx.x * 32 + nl;
    float a0[8], a1[8], a2[8], a3[8];
#pragma unroll
    for (int q = 0; q < 8; ++q) { a0[q] = 0.f; a1[q] = 0.f; a2[q] = 0.f; a3[q] = 0.f; }
    if (node < n) {
        const float di = dinv[node];
        const uint4 sv = *reinterpret_cast<const uint4*>(&X[(long long)node * 32 + j * 4]);
        BF_ADD8(a0, sv);
        const int* bp = cs + (node << 6);
        int end = cnt[node]; end = (end < CAP) ? end : CAP;
        int e = 0;
        for (; e + 4 <= end; e += 4) {
            const int s0 = bp[e], s1 = bp[e + 1], s2 = bp[e + 2], s3 = bp[e + 3];
            const uint4 h0 = *reinterpret_cast<const uint4*>(&X[(long long)s0 * 32 + j * 4]);
            const uint4 h1 = *reinterpret_cast<const uint4*>(&X[(long long)s1 * 32 + j * 4]);
            const uint4 h2 = *reinterpret_cast<const uint4*>(&X[(long long)s2 * 32 + j * 4]);
            const uint4 h3 = *reinterpret_cast<const uint4*>(&X[(long long)s3 * 32 + j * 4]);
            BF_ADD8(a0, h0);
            BF_ADD8(a1, h1);
            BF_ADD8(a2, h2);
            BF_ADD8(a3, h3);
        }
        if (e + 2 <= end) {
            const int s0 = bp[e], s1 = bp[e + 1];
            const uint4 h0 = *reinterpret_cast<const uint4*>(&X[(long long)s0 * 32 + j * 4]);
            const uint4 h1 = *reinterpret_cast<const uint4*>(&X[(long long)s1 * 32 + j * 4]);
            BF_ADD8(a0, h0);
            BF_ADD8(a1, h1);
            e += 2;
        }
        if (e < end) {
            const int s0 = bp[e];
            const uint4 h0 = *reinterpret_cast<const uint4*>(&X[(long long)s0 * 32 + j * 4]);
            BF_ADD8(a0, h0);
        }
#pragma unroll
        for (int q = 0; q < 8; ++q) a0[q] = di * (a0[q] + a1[q] + a2[q] + a3[q]);
    }
    *reinterpret_cast<float4*>(&agg[nl * AS + j * 8]) =
        make_float4(a0[0], a0[1], a0[2], a0[3]);
    *reinterpret_cast<float4*>(&agg[nl * AS + j * 8 + 4]) =
        make_float4(a0[4], a0[5], a0[6], a0[7]);
#pragma unroll
    for (int i = 0; i < 8; ++i)
        *reinterpret_cast<float4*>(&Wl[(threadIdx.x + i * 256) * 4]) = wr[i];
    __syncthreads();

    // phase B: K=64, F=128, 4 rows x 4 cols
    const int r0 = (threadIdx.x >> 5) * 4;
    const int cg = (threadIdx.x & 31) * 4;
    float4 o0 = make_float4(0.f, 0.f, 0.f, 0.f);
    float4 o1 = o0, o2 = o0, o3 = o0;
#pragma unroll 8
    for (int k = 0; k < 64; ++k) {
        const float4 wv = *reinterpret_cast<const float4*>(&Wl[k * 128 + cg]);
        const float x0 = agg[(r0 + 0) * AS + k];
        const float x1 = agg[(r0 + 1) * AS + k];
        const float x2 = agg[(r0 + 2) * AS + k];
        const float x3 = agg[(r0 + 3) * AS + k];
        FMA4(o0, wv, x0);
        FMA4(o1, wv, x1);
        FMA4(o2, wv, x2);
        FMA4(o3, wv, x3);
    }
    const float4 bv = *reinterpret_cast<const float4*>(&bias[cg]);
    const int row0 = blockIdx.x * 32 + r0;
    float4 oo[4] = {o0, o1, o2, o3};
#pragma unroll
    for (int r = 0; r < 4; ++r) {
        if (row0 + r < n) {
            const float dr = dinv[row0 + r];
            float ox = fmaxf(oo[r].x + bv.x, 0.f) * dr;
            float oy = fmaxf(oo[r].y + bv.y, 0.f) * dr;
            float oz = fmaxf(oo[r].z + bv.z, 0.f) * dr;
            float ow = fmaxf(oo[r].w + bv.w, 0.f) * dr;
            *reinterpret_cast<uint2*>(&out[(long long)(row0 + r) * 64 + (cg >> 1)]) =
                make_uint2(pack_bf2(ox, oy), pack_bf2(oz, ow));
        }
    }
}

// ---------------- fused layer-3 gather + pool partials ----------------------
__device__ __forceinline__ int lower_bound_i(const int* __restrict__ a, int n, int key) {
    int lo = 0, hi = n;
    while (lo < hi) {
        int mid = (lo + hi) >> 1;
        if (a[mid] < key) lo = mid + 1; else hi = mid;
    }
    return lo;
}

__global__ __launch_bounds__(256) void gather_pool(const u32* __restrict__ H,
                                                   const int* __restrict__ cnt,
                                                   const int* __restrict__ cs,
                                                   const float* __restrict__ dinv,
                                                   const int* __restrict__ batch,
                                                   float* __restrict__ Spart, int n) {
    __shared__ float red[16 * 128];
    const int g = blockIdx.x / PARTS;
    const int part = blockIdx.x % PARTS;
    const int slot = threadIdx.x >> 4;     // 16 slots
    const int j = threadIdx.x & 15;        // feature octet 0..15
    const int start = lower_bound_i(batch, n, g);
    const int end = lower_bound_i(batch, n, g + 1);
    float acc[8];
#pragma unroll
    for (int q = 0; q < 8; ++q) acc[q] = 0.f;
    for (int node = start + part * 16 + slot; node < end; node += PARTS * 16) {
        const float di = dinv[node];
        float t0[8], t1[8], t2[8], t3[8];
#pragma unroll
        for (int q = 0; q < 8; ++q) { t0[q] = 0.f; t1[q] = 0.f; t2[q] = 0.f; t3[q] = 0.f; }
        const uint4 sv = *reinterpret_cast<const uint4*>(&H[(long long)node * 64 + j * 4]);
        BF_ADD8(t0, sv);
        const int* bp = cs + (node << 6);
        int eend = cnt[node]; eend = (eend < CAP) ? eend : CAP;
        int e = 0;
        for (; e + 4 <= eend; e += 4) {
            const int s0 = bp[e], s1 = bp[e + 1], s2 = bp[e + 2], s3 = bp[e + 3];
            const uint4 h0 = *reinterpret_cast<const uint4*>(&H[(long long)s0 * 64 + j * 4]);
            const uint4 h1 = *reinterpret_cast<const uint4*>(&H[(long long)s1 * 64 + j * 4]);
            const uint4 h2 = *reinterpret_cast<const uint4*>(&H[(long long)s2 * 64 + j * 4]);
            const uint4 h3 = *reinterpret_cast<const uint4*>(&H[(long long)s3 * 64 + j * 4]);
            BF_ADD8(t0, h0);
            BF_ADD8(t1, h1);
            BF_ADD8(t2, h2);
            BF_ADD8(t3, h3);
        }
        if (e + 2 <= eend) {
            const int s0 = bp[e], s1 = bp[e + 1];
            const uint4 h0 = *reinterpret_cast<const uint4*>(&H[(long long)s0 * 64 + j * 4]);
            const uint4 h1 = *reinterpret_cast<const uint4*>(&H[(long long)s1 * 64 + j * 4]);
            BF_ADD8(t0, h0);
            BF_ADD8(t1, h1);
            e += 2;
        }
        if (e < eend) {
            const int s0 = bp[e];
            const uint4 h0 = *reinterpret_cast<const uint4*>(&H[(long long)s0 * 64 + j * 4]);
            BF_ADD8(t0, h0);
        }
#pragma unroll
        for (int q = 0; q < 8; ++q) acc[q] += di * (t0[q] + t1[q] + t2[q] + t3[q]);
    }
    *reinterpret_cast<float4*>(&red[slot * 128 + j * 8]) =
        make_float4(acc[0], acc[1], acc[2], acc[3]);
    *reinterpret_cast<float4*>(&red[slot * 128 + j * 8 + 4]) =
        make_float4(acc[4], acc[5], acc[6], acc[7]);
    __syncthreads();
    const int t = threadIdx.x;
    if (t < 128) {
        float s = 0.f;
#pragma unroll
        for (int sl = 0; sl < 16; ++sl) s += red[sl * 128 + t];
        Spart[(long long)blockIdx.x * 128 + t] = s;
    }
}

// ---------------- final ----------------
__global__ __launch_bounds__(256) void final_k(const float* __restrict__ Spart,
                                               const int* __restrict__ batch,
                                               const float* __restrict__ W3,
                                               const float* __restrict__ b3,
                                               const float* __restrict__ Wlin,
                                               const float* __restrict__ blin,
                                               float* __restrict__ out, int n) {
    __shared__ float srow[128];
    __shared__ float prow[256];
    const int g = blockIdx.x;
    const int t = threadIdx.x;
    if (t < 128) {
        float s = 0.f;
#pragma unroll
        for (int p = 0; p < PARTS; ++p)
            s += Spart[(long long)(g * PARTS + p) * 128 + t];
        srow[t] = s;
    }
    __syncthreads();
    const int start = lower_bound_i(batch, n, g);
    const int end = lower_bound_i(batch, n, g + 1);
    const float cnt = (float)(end - start);
    const float inv = 1.0f / fmaxf(cnt, 1.0f);
    const float bscale = cnt * inv;
    float p = 0.f;
    for (int k = 0; k < 128; ++k) p += srow[k] * W3[k * 256 + t];
    prow[t] = p * inv + b3[t] * bscale;
    __syncthreads();
    if (t < 10) {
        float a = blin[t];
        for (int f = 0; f < 256; ++f) a += prow[f] * Wlin[f * 10 + t];
        out[g * 10 + t] = a;
    }
}

extern "C" void kernel_launch(void* const* d_in, const int* in_sizes, int n_in,
                              void* d_out, int out_size, void* d_ws, size_t ws_size,
                              hipStream_t stream) {
    const float* x     = (const float*)d_in[0];
    const int*   ei    = (const int*)d_in[1];
    const int*   batch = (const int*)d_in[2];
    const float* W1    = (const float*)d_in[3];
    const float* bc1   = (const float*)d_in[4];
    const float* W2    = (const float*)d_in[5];
    const float* bc2   = (const float*)d_in[6];
    const float* W3    = (const float*)d_in[7];
    const float* bc3   = (const float*)d_in[8];
    const float* Wlin  = (const float*)d_in[9];
    const float* blin  = (const float*)d_in[10];
    float* out = (float*)d_out;

    char* w = (char*)d_ws;
    int*   cnt    = (int*)w;               w += 131072 * 4;
    float* dinv   = (float*)w;             w += 131072 * 4;
    int*   cs     = (int*)w;               w += (long long)NN * CAP * 4;  // buckets
    u32*   xg     = (u32*)w;               w += (long long)NN * 16 * 4;   // x*dinv bf16
    u32*   Q      = (u32*)w;               w += (long long)NN * 32 * 4;   // g1 bf16
    u32*   P      = (u32*)w;               w += (long long)NN * 64 * 4;   // g2 bf16
    float* Spart  = (float*)w;             w += (long long)NG * PARTS * 128 * 4;

    hipMemsetAsync(cnt, 0, NN * sizeof(int), stream);
    fill_bucket<<<(NE + 255) / 256, 256, 0, stream>>>(ei, cnt, cs, NE);
    prep<<<(NN * 8 + 255) / 256, 256, 0, stream>>>(x, cnt, dinv, xg, NN * 8);

    gather_gemm_l1<<<(NN + 31) / 32, 256, 0, stream>>>(xg, cnt, cs, dinv, W1, bc1, Q, NN);
    gather_gemm_l2<<<(NN + 31) / 32, 256, 0, stream>>>(Q, cnt, cs, dinv, W2, bc2, P, NN);
    gather_pool<<<NG * PARTS, 256, 0, stream>>>(P, cnt, cs, dinv, batch, Spart, NN);
    final_k<<<NG, 256, 0, stream>>>(Spart, batch, W3, bc3, Wlin, blin, out, NN);
}